// Round 8
// baseline (272.827 us; speedup 1.0000x reference)
//
#include <hip/hip_runtime.h>

// SpectralAttention: y = (softmax_causal((xWq^T)(xWk^T)^T/8) (xWv^T)) Wo^T
// B=4 T=2048 C=1024 H=16 hd=64.
// R8 = R7 with attn kv-tile 128 (two 64-kv halves per staged tile, half the
// barriers; K/V/P LDS patterns identical to the measured-0-conflict ones),
// LDS 48KB -> 3 blocks/CU, and cvt_x+cvt_w4 merged into one launch.

#define B_ 4
#define T_ 2048
#define C_ 1024
#define H_ 16
#define M_ 8192  // B*T

typedef unsigned short u16;
typedef __bf16 bf16x8 __attribute__((ext_vector_type(8)));
typedef float f32x4 __attribute__((ext_vector_type(4)));

static __device__ __forceinline__ u16 f2bf(float f) {
  unsigned int u = __float_as_uint(f);
  u += 0x7fffu + ((u >> 16) & 1u);  // RNE; inputs finite
  return (u16)(u >> 16);
}

static __device__ __forceinline__ void async16(const void* g, void* l) {
  __builtin_amdgcn_global_load_lds(
      (const __attribute__((address_space(1))) unsigned int*)g,
      (__attribute__((address_space(3))) unsigned int*)l, 16, 0, 0);
}

#if __has_builtin(__builtin_amdgcn_exp2f)
#define EXP2F(x) __builtin_amdgcn_exp2f(x)
#else
#define EXP2F(x) exp2f(x)
#endif

static __device__ __forceinline__ f32x4 mfma32(bf16x8 a, bf16x8 b, f32x4 c) {
  return __builtin_amdgcn_mfma_f32_16x16x32_bf16(a, b, c, 0, 0, 0);
}

// ---------------- fp32 -> bf16, all 5 tensors in one launch ----------------
// regions: [0, NX) = x ; then 4 weight matrices (w0 scaled by s0).
__global__ __launch_bounds__(256) void cvt_all(const float* __restrict__ x,
                                               const float* __restrict__ w0,
                                               const float* __restrict__ w1,
                                               const float* __restrict__ w2,
                                               const float* __restrict__ w3,
                                               u16* __restrict__ xb,
                                               u16* __restrict__ wb,  // 4 mats contig
                                               float s0) {
  const int NX = M_ * C_ / 4, NW = C_ * C_ / 4;
  int i = blockIdx.x * 256 + threadIdx.x;
  const float* src;
  u16* dst;
  int idx;
  float s = 1.f;
  if (i < NX) {
    src = x; dst = xb; idx = i;
  } else {
    int j = i - NX;
    int w = j / NW;
    idx = j - w * NW;
    src = (w == 0) ? w0 : (w == 1) ? w1 : (w == 2) ? w2 : w3;
    dst = wb + (size_t)w * C_ * C_;
    if (w == 0) s = s0;
  }
  float4 f = ((const float4*)src)[idx];
  ushort4 o;
  o.x = f2bf(f.x * s); o.y = f2bf(f.y * s); o.z = f2bf(f.z * s); o.w = f2bf(f.w * s);
  ((ushort4*)dst)[idx] = o;
}

// ---------------- merged QKV projection (unchanged from R7) ----------------
__global__ __launch_bounds__(256, 4) void gemm_qkv(const u16* __restrict__ A,
                                                   const u16* __restrict__ W,
                                                   const float* __restrict__ bq,
                                                   const float* __restrict__ bk,
                                                   const float* __restrict__ bv,
                                                   float qscale,
                                                   u16* __restrict__ outqk,
                                                   u16* __restrict__ vtb) {
  __shared__ __align__(16) union {
    struct { u16 A[128 * 64]; u16 B[128 * 64]; } s;
    u16 C[128 * 136];
  } sm;
  const int tid = threadIdx.x, lane = tid & 63, wave = tid >> 6;
  const int quad = lane >> 4, l16 = lane & 15;
  const int wm = wave >> 1, wn = wave & 1;
  const int sel = blockIdx.x >> 3;
  const int col0 = (blockIdx.x & 7) * 128, row0 = blockIdx.y * 128;
  const u16* Bt = W + (size_t)sel * C_ * C_;
  const float* bias = sel == 0 ? bq : (sel == 1 ? bk : bv);
  const float bscale = sel == 0 ? qscale : 1.f;

  f32x4 zero = {0.f, 0.f, 0.f, 0.f};
  f32x4 acc[4][4];
#pragma unroll
  for (int i = 0; i < 4; i++)
#pragma unroll
    for (int j = 0; j < 4; j++) acc[i][j] = zero;

  for (int k0 = 0; k0 < C_; k0 += 64) {
#pragma unroll
    for (int i = 0; i < 4; i++) {
      int c = i * 256 + tid;
      int r = c >> 3, gcc = (c & 7) ^ (r & 7);
      async16(A + (size_t)(row0 + r) * C_ + k0 + gcc * 8,
              sm.s.A + (size_t)(i * 256 + wave * 64) * 8);
      async16(Bt + (size_t)(col0 + r) * C_ + k0 + gcc * 8,
              sm.s.B + (size_t)(i * 256 + wave * 64) * 8);
    }
    __syncthreads();

#pragma unroll
    for (int kk = 0; kk < 2; kk++) {
      bf16x8 a[4], b[4];
#pragma unroll
      for (int i = 0; i < 4; i++) {
        int rm = wm * 64 + 16 * i + l16;
        a[i] = *(const bf16x8*)(sm.s.A + rm * 64 + (((kk * 4 + quad) ^ (rm & 7)) * 8));
        int rn = wn * 64 + 16 * i + l16;
        b[i] = *(const bf16x8*)(sm.s.B + rn * 64 + (((kk * 4 + quad) ^ (rn & 7)) * 8));
      }
#pragma unroll
      for (int i = 0; i < 4; i++)
#pragma unroll
        for (int j = 0; j < 4; j++)
          acc[i][j] = mfma32(a[i], b[j], acc[i][j]);
    }
    __syncthreads();
  }

  float bj[4];
#pragma unroll
  for (int j = 0; j < 4; j++) bj[j] = bias[col0 + wn * 64 + 16 * j + l16] * bscale;

  if (sel == 2) {
#pragma unroll
    for (int i = 0; i < 4; i++)
#pragma unroll
      for (int j = 0; j < 4; j++) {
        int cl = wn * 64 + 16 * j + l16;
        int rt = wm * 64 + 16 * i + quad * 4;
        union { u16 s[4]; uint2 u; } w;
#pragma unroll
        for (int r = 0; r < 4; r++) w.s[r] = f2bf(acc[i][j][r] + bj[j]);
        *(uint2*)(sm.C + (size_t)cl * 136 + rt) = w.u;
      }
    __syncthreads();
    const int bb = row0 >> 11, t0 = row0 & 2047;
#pragma unroll
    for (int c2 = 0; c2 < 8; c2++) {
      int c = c2 * 256 + tid;
      int nr = c >> 4, ch = c & 15;
      bf16x8 v = *(const bf16x8*)(sm.C + (size_t)nr * 136 + ch * 8);
      int gn = col0 + nr, d = gn & 63, hh = gn >> 6;
      *(bf16x8*)(vtb + ((size_t)((bb * 16 + hh) * 64 + d)) * T_ + t0 + ch * 8) = v;
    }
  } else {
#pragma unroll
    for (int i = 0; i < 4; i++)
#pragma unroll
      for (int j = 0; j < 4; j++) {
        int cl = wn * 64 + 16 * j + l16;
        int rt = wm * 64 + 16 * i + quad * 4;
#pragma unroll
        for (int r = 0; r < 4; r++)
          sm.C[(size_t)(rt + r) * 136 + cl] = f2bf(acc[i][j][r] + bj[j]);
      }
    __syncthreads();
    u16* dst = outqk + (size_t)sel * M_ * C_;
#pragma unroll
    for (int c2 = 0; c2 < 8; c2++) {
      int c = c2 * 256 + tid;
      int rw = c >> 4, ch = c & 15;
      bf16x8 v = *(const bf16x8*)(sm.C + (size_t)rw * 136 + ch * 8);
      *(bf16x8*)(dst + (size_t)(row0 + rw) * C_ + col0 + ch * 8) = v;
    }
  }
}

// ---------------- output projection (unchanged from R7) ----------------
__global__ __launch_bounds__(256) void gemm_o(const u16* __restrict__ A,
                                              const u16* __restrict__ Bt,
                                              const float* __restrict__ bias,
                                              float* __restrict__ outf) {
  __shared__ __align__(16) u16 Asm[128 * 64];
  __shared__ __align__(16) u16 Bsm[128 * 64];
  const int tid = threadIdx.x, lane = tid & 63, wave = tid >> 6;
  const int quad = lane >> 4, l16 = lane & 15;
  const int wm = wave >> 1, wn = wave & 1;
  const int col0 = blockIdx.x * 128, row0 = blockIdx.y * 128;

  f32x4 zero = {0.f, 0.f, 0.f, 0.f};
  f32x4 acc[4][4];
#pragma unroll
  for (int i = 0; i < 4; i++)
#pragma unroll
    for (int j = 0; j < 4; j++) acc[i][j] = zero;

  for (int k0 = 0; k0 < C_; k0 += 64) {
#pragma unroll
    for (int i = 0; i < 4; i++) {
      int c = i * 256 + tid;
      int r = c >> 3, gcc = (c & 7) ^ (r & 7);
      async16(A + (size_t)(row0 + r) * C_ + k0 + gcc * 8,
              Asm + (size_t)(i * 256 + wave * 64) * 8);
      async16(Bt + (size_t)(col0 + r) * C_ + k0 + gcc * 8,
              Bsm + (size_t)(i * 256 + wave * 64) * 8);
    }
    __syncthreads();

#pragma unroll
    for (int kk = 0; kk < 2; kk++) {
      bf16x8 a[4], b[4];
#pragma unroll
      for (int i = 0; i < 4; i++) {
        int rm = wm * 64 + 16 * i + l16;
        a[i] = *(const bf16x8*)(Asm + rm * 64 + (((kk * 4 + quad) ^ (rm & 7)) * 8));
        int rn = wn * 64 + 16 * i + l16;
        b[i] = *(const bf16x8*)(Bsm + rn * 64 + (((kk * 4 + quad) ^ (rn & 7)) * 8));
      }
#pragma unroll
      for (int i = 0; i < 4; i++)
#pragma unroll
        for (int j = 0; j < 4; j++)
          acc[i][j] = mfma32(a[i], b[j], acc[i][j]);
    }
    __syncthreads();
  }

  float bj[4];
#pragma unroll
  for (int j = 0; j < 4; j++) bj[j] = bias[col0 + wn * 64 + 16 * j + l16];
#pragma unroll
  for (int i = 0; i < 4; i++) {
#pragma unroll
    for (int j = 0; j < 4; j++) {
      int gcol = col0 + wn * 64 + 16 * j + l16;
      int grow0 = row0 + wm * 64 + 16 * i + quad * 4;
#pragma unroll
      for (int r = 0; r < 4; r++)
        outf[(size_t)(grow0 + r) * C_ + gcol] = acc[i][j][r] + bj[j];
    }
  }
}

// ---------------- flash attention (causal), kv-tile 128 ----------------
// Block: 128 q rows (4 waves x 32). Per staged tile: K[128kv][64d] (rows 64
// u16, phys chunk = c^(r&7)); V^T as 2 subtiles [64d][64kv] (same pattern);
// two 64-kv compute halves reuse per-wave P [32q][64kv] (DS in-order).
// Diag tile is the last (jt==qt); fully-masked halves/subtiles skipped.
__global__ __launch_bounds__(256) void attn(const u16* __restrict__ q,
                                            const u16* __restrict__ k,
                                            const u16* __restrict__ vt,
                                            u16* __restrict__ y) {
  __shared__ __align__(16) u16 Ksm[128 * 64];
  __shared__ __align__(16) u16 Vsm[2][64 * 64];
  __shared__ __align__(16) u16 Psm[4][32 * 64];
  const int tid = threadIdx.x, lane = tid & 63, wave = tid >> 6;
  const int quad = lane >> 4, l16 = lane & 15;
  static const int qperm[16] = {15, 14, 11, 10, 12, 13, 8, 9, 3, 2, 7, 6, 0, 1, 4, 5};
  const int bh = blockIdx.x;
  const int qt = qperm[blockIdx.y];
  const int b = bh >> 4, h = bh & 15;

  // Q fragments (A-operand: m=lane&15, k=quad*8+j), 2 sub-tiles of 16 q rows
  bf16x8 qf[2][2];
#pragma unroll
  for (int m = 0; m < 2; m++) {
    const u16* qp =
        q + (size_t)(b * T_ + qt * 128 + wave * 32 + m * 16 + l16) * C_ + h * 64;
#pragma unroll
    for (int ks = 0; ks < 2; ks++)
      qf[m][ks] = *(const bf16x8*)(qp + ks * 32 + quad * 8);
  }

  f32x4 zero = {0.f, 0.f, 0.f, 0.f};
  f32x4 o[2][4];
  float lp[2][4];
#pragma unroll
  for (int m = 0; m < 2; m++) {
#pragma unroll
    for (int dt = 0; dt < 4; dt++) o[m][dt] = zero;
#pragma unroll
    for (int r = 0; r < 4; r++) lp[m][r] = 0.f;
  }

  // staging pointers: K 4 chunks/thread (1024 total), V 2 subtiles x 2 chunks
  const u16* kp[4];
  const u16* vp[4];
#pragma unroll
  for (int i = 0; i < 4; i++) {
    int c = i * 256 + tid;            // 0..1023
    int r = c >> 3, lc = (c & 7) ^ (r & 7);
    kp[i] = k + (size_t)(b * T_ + r) * C_ + h * 64 + lc * 8;
  }
#pragma unroll
  for (int s = 0; s < 2; s++)
#pragma unroll
    for (int i = 0; i < 2; i++) {
      int c = i * 256 + tid;          // 0..511
      int r = c >> 3, lc = (c & 7) ^ (r & 7);
      vp[s * 2 + i] = vt + (size_t)(bh * 64 + r) * T_ + 64 * s + lc * 8;
    }

  // diag mask: q_rel = wave*32+m*16+quad*4+r, kv_rel = hh*64+n*16+l16
  int qrel[2];
#pragma unroll
  for (int m = 0; m < 2; m++)
    qrel[m] = wave * 32 + m * 16 + quad * 4 - l16;

  u16* Pw = &Psm[wave][0];

#pragma unroll 1
  for (int jt = 0; jt <= qt; ++jt) {
#pragma unroll
    for (int i = 0; i < 4; i++) {
      async16(kp[i], Ksm + (size_t)(i * 256 + wave * 64) * 8);
      kp[i] += (size_t)128 * C_;
    }
#pragma unroll
    for (int s = 0; s < 2; s++)
#pragma unroll
      for (int i = 0; i < 2; i++) {
        async16(vp[s * 2 + i], Vsm[s] + (size_t)(i * 256 + wave * 64) * 8);
        vp[s * 2 + i] += 128;
      }
    __syncthreads();  // drains vmcnt before LDS use

    const bool diag = (jt == qt);
#pragma unroll
    for (int hh = 0; hh < 2; ++hh) {
      if (diag && (2 * wave + 2 - 4 * hh) <= 0) continue;  // fully-masked half
      // ---- S = Q K^T (half hh), exp, write P ----
#pragma unroll
      for (int n = 0; n < 4; ++n) {
        int rk = hh * 64 + n * 16 + l16;
        bf16x8 kf0 = *(const bf16x8*)(Ksm + rk * 64 + ((quad ^ (rk & 7)) * 8));
        bf16x8 kf1 = *(const bf16x8*)(Ksm + rk * 64 + (((4 + quad) ^ (rk & 7)) * 8));
#pragma unroll
        for (int m = 0; m < 2; ++m) {
          int nlim = diag ? (2 * wave + m + 1 - 4 * hh) : 4;  // live n count
          if (n < nlim) {
            f32x4 s = mfma32(qf[m][0], kf0, zero);
            s = mfma32(qf[m][1], kf1, s);
            float e[4];
#pragma unroll
            for (int r = 0; r < 4; r++) e[r] = EXP2F(s[r]);
            if (diag) {
              int rmin = hh * 64 + n * 16 - qrel[m];
#pragma unroll
              for (int r = 0; r < 4; r++)
                if (r < rmin) e[r] = 0.f;  // kv > q -> masked
            }
#pragma unroll
            for (int r = 0; r < 4; r++) {
              lp[m][r] += e[r];
              int qr = m * 16 + quad * 4 + r;
              Pw[qr * 64 + (((n * 2 + (l16 >> 3)) ^ (qr & 7)) * 8) + (l16 & 7)] =
                  f2bf(e[r]);
            }
          } else {  // masked sub-tile on diagonal: zero P
#pragma unroll
            for (int r = 0; r < 4; r++) {
              int qr = m * 16 + quad * 4 + r;
              Pw[qr * 64 + (((n * 2 + (l16 >> 3)) ^ (qr & 7)) * 8) + (l16 & 7)] = 0;
            }
          }
        }
      }
      // ---- O += P V (half hh); same-wave DS ordering, no barrier ----
      bf16x8 pf[2][2];
#pragma unroll
      for (int m = 0; m < 2; m++)
#pragma unroll
        for (int ks = 0; ks < 2; ks++)
          pf[m][ks] = *(const bf16x8*)(Pw + (m * 16 + l16) * 64 +
                                       (((ks * 4 + quad) ^ (l16 & 7)) * 8));
#pragma unroll
      for (int dt = 0; dt < 4; ++dt) {
        int rv = dt * 16 + l16;
        bf16x8 vf0 = *(const bf16x8*)(Vsm[hh] + rv * 64 + ((quad ^ (rv & 7)) * 8));
        bf16x8 vf1 = *(const bf16x8*)(Vsm[hh] + rv * 64 + (((4 + quad) ^ (rv & 7)) * 8));
#pragma unroll
        for (int m = 0; m < 2; m++) {
          o[m][dt] = mfma32(pf[m][0], vf0, o[m][dt]);
          o[m][dt] = mfma32(pf[m][1], vf1, o[m][dt]);
        }
      }
    }
    __syncthreads();  // protect Ksm/Vsm before next stage
  }

  // deferred l-reduction (once per block)
#pragma unroll
  for (int m = 0; m < 2; m++)
#pragma unroll
    for (int r = 0; r < 4; r++) {
      float v = lp[m][r];
      v += __shfl_xor(v, 1);
      v += __shfl_xor(v, 2);
      v += __shfl_xor(v, 4);
      v += __shfl_xor(v, 8);
      lp[m][r] = 1.f / v;
    }

#pragma unroll
  for (int m = 0; m < 2; m++)
#pragma unroll
    for (int r = 0; r < 4; r++) {
      int grow = b * T_ + qt * 128 + wave * 32 + m * 16 + quad * 4 + r;
#pragma unroll
      for (int dt = 0; dt < 4; dt++)
        y[(size_t)grow * C_ + h * 64 + dt * 16 + l16] = f2bf(o[m][dt][r] * lp[m][r]);
    }
}

extern "C" void kernel_launch(void* const* d_in, const int* in_sizes, int n_in,
                              void* d_out, int out_size, void* d_ws, size_t ws_size,
                              hipStream_t stream) {
  const float* x  = (const float*)d_in[0];
  const float* wq = (const float*)d_in[1];
  const float* bq = (const float*)d_in[2];
  const float* wk = (const float*)d_in[3];
  const float* bk = (const float*)d_in[4];
  const float* wv = (const float*)d_in[5];
  const float* bv = (const float*)d_in[6];
  const float* wo = (const float*)d_in[7];
  const float* bo = (const float*)d_in[8];
  float* out = (float*)d_out;

  const float QSCALE = 0.125f * 1.4426950408889634f;  // hd^-0.5 * log2(e)

  u16* xb  = (u16*)d_ws;                    // [8192,1024]
  u16* wqb = xb  + (size_t)M_ * C_;         // [1024,1024] x4 (wq|wk|wv|wo contig)
  u16* wob = wqb + 3 * (size_t)C_ * C_;
  u16* qb  = wob + (size_t)C_ * C_;         // [8192,1024] (qb|kb contiguous)
  u16* kb  = qb  + (size_t)M_ * C_;
  u16* vtb = kb  + (size_t)M_ * C_;         // [(b*16+h)*64+d][2048]
  u16* yb  = xb;  // xb dead after QKV projections

  const int NCVT = (M_ * C_ + 4 * C_ * C_) / 4 / 256;  // 12288 blocks
  cvt_all<<<NCVT, 256, 0, stream>>>(x, wq, wk, wv, wo, xb, wqb, QSCALE);

  gemm_qkv<<<dim3(24, M_ / 128), 256, 0, stream>>>(xb, wqb, bq, bk, bv, QSCALE,
                                                   qb, vtb);

  attn<<<dim3(B_ * H_, 16), 256, 0, stream>>>(qb, kb, vtb, yb);

  gemm_o<<<dim3(C_ / 128, M_ / 128), 256, 0, stream>>>(yb, wob, bo, out);
}

// Round 9
// 261.742 us; speedup vs baseline: 1.0424x; 1.0424x over previous
//
#include <hip/hip_runtime.h>

// SpectralAttention: y = (softmax_causal((xWq^T)(xWk^T)^T/8) (xWv^T)) Wo^T
// B=4 T=2048 C=1024 H=16 hd=64.
// R9 = R8 with GEMM fixes (attn/cvt unchanged):
//  - gemm_qkv: launch_bounds VGPR cap removed (suspected spills at <=128)
//  - gemm_o: 2-phase LDS-coalesced fp32 epilogue (float4 stores, 132-f pad)

#define B_ 4
#define T_ 2048
#define C_ 1024
#define H_ 16
#define M_ 8192  // B*T

typedef unsigned short u16;
typedef __bf16 bf16x8 __attribute__((ext_vector_type(8)));
typedef float f32x4 __attribute__((ext_vector_type(4)));

static __device__ __forceinline__ u16 f2bf(float f) {
  unsigned int u = __float_as_uint(f);
  u += 0x7fffu + ((u >> 16) & 1u);  // RNE; inputs finite
  return (u16)(u >> 16);
}

static __device__ __forceinline__ void async16(const void* g, void* l) {
  __builtin_amdgcn_global_load_lds(
      (const __attribute__((address_space(1))) unsigned int*)g,
      (__attribute__((address_space(3))) unsigned int*)l, 16, 0, 0);
}

#if __has_builtin(__builtin_amdgcn_exp2f)
#define EXP2F(x) __builtin_amdgcn_exp2f(x)
#else
#define EXP2F(x) exp2f(x)
#endif

static __device__ __forceinline__ f32x4 mfma32(bf16x8 a, bf16x8 b, f32x4 c) {
  return __builtin_amdgcn_mfma_f32_16x16x32_bf16(a, b, c, 0, 0, 0);
}

// ---------------- fp32 -> bf16, all 5 tensors in one launch ----------------
__global__ __launch_bounds__(256) void cvt_all(const float* __restrict__ x,
                                               const float* __restrict__ w0,
                                               const float* __restrict__ w1,
                                               const float* __restrict__ w2,
                                               const float* __restrict__ w3,
                                               u16* __restrict__ xb,
                                               u16* __restrict__ wb,  // 4 mats contig
                                               float s0) {
  const int NX = M_ * C_ / 4, NW = C_ * C_ / 4;
  int i = blockIdx.x * 256 + threadIdx.x;
  const float* src;
  u16* dst;
  int idx;
  float s = 1.f;
  if (i < NX) {
    src = x; dst = xb; idx = i;
  } else {
    int j = i - NX;
    int w = j / NW;
    idx = j - w * NW;
    src = (w == 0) ? w0 : (w == 1) ? w1 : (w == 2) ? w2 : w3;
    dst = wb + (size_t)w * C_ * C_;
    if (w == 0) s = s0;
  }
  float4 f = ((const float4*)src)[idx];
  ushort4 o;
  o.x = f2bf(f.x * s); o.y = f2bf(f.y * s); o.z = f2bf(f.z * s); o.w = f2bf(f.w * s);
  ((ushort4*)dst)[idx] = o;
}

// ---------------- merged QKV projection ----------------
// out[sel][m,n] = sum_k x[m,k] W[sel][n,k] + bias[sel][n], sel = bx>>3.
// 128x128 tile, BK=64. Staging LDS rows 64 u16 (8 chunks), phys=c^(r&7).
__global__ __launch_bounds__(256) void gemm_qkv(const u16* __restrict__ A,
                                                const u16* __restrict__ W,
                                                const float* __restrict__ bq,
                                                const float* __restrict__ bk,
                                                const float* __restrict__ bv,
                                                float qscale,
                                                u16* __restrict__ outqk,
                                                u16* __restrict__ vtb) {
  __shared__ __align__(16) union {
    struct { u16 A[128 * 64]; u16 B[128 * 64]; } s;
    u16 C[128 * 136];
  } sm;
  const int tid = threadIdx.x, lane = tid & 63, wave = tid >> 6;
  const int quad = lane >> 4, l16 = lane & 15;
  const int wm = wave >> 1, wn = wave & 1;
  const int sel = blockIdx.x >> 3;
  const int col0 = (blockIdx.x & 7) * 128, row0 = blockIdx.y * 128;
  const u16* Bt = W + (size_t)sel * C_ * C_;
  const float* bias = sel == 0 ? bq : (sel == 1 ? bk : bv);
  const float bscale = sel == 0 ? qscale : 1.f;

  f32x4 zero = {0.f, 0.f, 0.f, 0.f};
  f32x4 acc[4][4];
#pragma unroll
  for (int i = 0; i < 4; i++)
#pragma unroll
    for (int j = 0; j < 4; j++) acc[i][j] = zero;

  for (int k0 = 0; k0 < C_; k0 += 64) {
#pragma unroll
    for (int i = 0; i < 4; i++) {
      int c = i * 256 + tid;
      int r = c >> 3, gcc = (c & 7) ^ (r & 7);
      async16(A + (size_t)(row0 + r) * C_ + k0 + gcc * 8,
              sm.s.A + (size_t)(i * 256 + wave * 64) * 8);
      async16(Bt + (size_t)(col0 + r) * C_ + k0 + gcc * 8,
              sm.s.B + (size_t)(i * 256 + wave * 64) * 8);
    }
    __syncthreads();

#pragma unroll
    for (int kk = 0; kk < 2; kk++) {
      bf16x8 a[4], b[4];
#pragma unroll
      for (int i = 0; i < 4; i++) {
        int rm = wm * 64 + 16 * i + l16;
        a[i] = *(const bf16x8*)(sm.s.A + rm * 64 + (((kk * 4 + quad) ^ (rm & 7)) * 8));
        int rn = wn * 64 + 16 * i + l16;
        b[i] = *(const bf16x8*)(sm.s.B + rn * 64 + (((kk * 4 + quad) ^ (rn & 7)) * 8));
      }
#pragma unroll
      for (int i = 0; i < 4; i++)
#pragma unroll
        for (int j = 0; j < 4; j++)
          acc[i][j] = mfma32(a[i], b[j], acc[i][j]);
    }
    __syncthreads();
  }

  float bj[4];
#pragma unroll
  for (int j = 0; j < 4; j++) bj[j] = bias[col0 + wn * 64 + 16 * j + l16] * bscale;

  if (sel == 2) {
#pragma unroll
    for (int i = 0; i < 4; i++)
#pragma unroll
      for (int j = 0; j < 4; j++) {
        int cl = wn * 64 + 16 * j + l16;
        int rt = wm * 64 + 16 * i + quad * 4;
        union { u16 s[4]; uint2 u; } w;
#pragma unroll
        for (int r = 0; r < 4; r++) w.s[r] = f2bf(acc[i][j][r] + bj[j]);
        *(uint2*)(sm.C + (size_t)cl * 136 + rt) = w.u;
      }
    __syncthreads();
    const int bb = row0 >> 11, t0 = row0 & 2047;
#pragma unroll
    for (int c2 = 0; c2 < 8; c2++) {
      int c = c2 * 256 + tid;
      int nr = c >> 4, ch = c & 15;
      bf16x8 v = *(const bf16x8*)(sm.C + (size_t)nr * 136 + ch * 8);
      int gn = col0 + nr, d = gn & 63, hh = gn >> 6;
      *(bf16x8*)(vtb + ((size_t)((bb * 16 + hh) * 64 + d)) * T_ + t0 + ch * 8) = v;
    }
  } else {
#pragma unroll
    for (int i = 0; i < 4; i++)
#pragma unroll
      for (int j = 0; j < 4; j++) {
        int cl = wn * 64 + 16 * j + l16;
        int rt = wm * 64 + 16 * i + quad * 4;
#pragma unroll
        for (int r = 0; r < 4; r++)
          sm.C[(size_t)(rt + r) * 136 + cl] = f2bf(acc[i][j][r] + bj[j]);
      }
    __syncthreads();
    u16* dst = outqk + (size_t)sel * M_ * C_;
#pragma unroll
    for (int c2 = 0; c2 < 8; c2++) {
      int c = c2 * 256 + tid;
      int rw = c >> 4, ch = c & 15;
      bf16x8 v = *(const bf16x8*)(sm.C + (size_t)rw * 136 + ch * 8);
      *(bf16x8*)(dst + (size_t)(row0 + rw) * C_ + col0 + ch * 8) = v;
    }
  }
}

// ---------------- output projection: out = y Wo^T + bo (fp32 out) ----------------
// R9: 2-phase LDS epilogue -> coalesced float4 stores (was 64 scattered dwords).
__global__ __launch_bounds__(256) void gemm_o(const u16* __restrict__ A,
                                              const u16* __restrict__ Bt,
                                              const float* __restrict__ bias,
                                              float* __restrict__ outf) {
  __shared__ __align__(16) union {
    struct { u16 A[128 * 64]; u16 B[128 * 64]; } s;
    float Cf[64 * 132];
  } sm;
  const int tid = threadIdx.x, lane = tid & 63, wave = tid >> 6;
  const int quad = lane >> 4, l16 = lane & 15;
  const int wm = wave >> 1, wn = wave & 1;
  const int col0 = blockIdx.x * 128, row0 = blockIdx.y * 128;

  f32x4 zero = {0.f, 0.f, 0.f, 0.f};
  f32x4 acc[4][4];
#pragma unroll
  for (int i = 0; i < 4; i++)
#pragma unroll
    for (int j = 0; j < 4; j++) acc[i][j] = zero;

  for (int k0 = 0; k0 < C_; k0 += 64) {
#pragma unroll
    for (int i = 0; i < 4; i++) {
      int c = i * 256 + tid;
      int r = c >> 3, gcc = (c & 7) ^ (r & 7);
      async16(A + (size_t)(row0 + r) * C_ + k0 + gcc * 8,
              sm.s.A + (size_t)(i * 256 + wave * 64) * 8);
      async16(Bt + (size_t)(col0 + r) * C_ + k0 + gcc * 8,
              sm.s.B + (size_t)(i * 256 + wave * 64) * 8);
    }
    __syncthreads();

#pragma unroll
    for (int kk = 0; kk < 2; kk++) {
      bf16x8 a[4], b[4];
#pragma unroll
      for (int i = 0; i < 4; i++) {
        int rm = wm * 64 + 16 * i + l16;
        a[i] = *(const bf16x8*)(sm.s.A + rm * 64 + (((kk * 4 + quad) ^ (rm & 7)) * 8));
        int rn = wn * 64 + 16 * i + l16;
        b[i] = *(const bf16x8*)(sm.s.B + rn * 64 + (((kk * 4 + quad) ^ (rn & 7)) * 8));
      }
#pragma unroll
      for (int i = 0; i < 4; i++)
#pragma unroll
        for (int j = 0; j < 4; j++)
          acc[i][j] = mfma32(a[i], b[j], acc[i][j]);
    }
    __syncthreads();
  }

  float bj[4];
#pragma unroll
  for (int j = 0; j < 4; j++) bj[j] = bias[col0 + wn * 64 + 16 * j + l16];

#pragma unroll
  for (int cc = 0; cc < 2; cc++) {
    if (cc) __syncthreads();  // protect Cf between chunks (K-loop barrier covers cc=0)
    if (wm == cc) {
#pragma unroll
      for (int i = 0; i < 4; i++)
#pragma unroll
        for (int j = 0; j < 4; j++) {
          int cl = wn * 64 + 16 * j + l16;
          int rl = 16 * i + quad * 4;
#pragma unroll
          for (int r = 0; r < 4; r++)
            sm.Cf[(size_t)(rl + r) * 132 + cl] = acc[i][j][r] + bj[j];
        }
    }
    __syncthreads();
#pragma unroll
    for (int f2 = 0; f2 < 8; f2++) {
      int f = f2 * 256 + tid;           // 0..2047 float4s
      int rl = f >> 5, c4 = f & 31;
      float4 v = *(const float4*)(sm.Cf + (size_t)rl * 132 + c4 * 4);
      *(float4*)(outf + (size_t)(row0 + cc * 64 + rl) * C_ + col0 + c4 * 4) = v;
    }
  }
}

// ---------------- flash attention (causal), kv-tile 128 — unchanged (R8, ~80us) ----
__global__ __launch_bounds__(256) void attn(const u16* __restrict__ q,
                                            const u16* __restrict__ k,
                                            const u16* __restrict__ vt,
                                            u16* __restrict__ y) {
  __shared__ __align__(16) u16 Ksm[128 * 64];
  __shared__ __align__(16) u16 Vsm[2][64 * 64];
  __shared__ __align__(16) u16 Psm[4][32 * 64];
  const int tid = threadIdx.x, lane = tid & 63, wave = tid >> 6;
  const int quad = lane >> 4, l16 = lane & 15;
  static const int qperm[16] = {15, 14, 11, 10, 12, 13, 8, 9, 3, 2, 7, 6, 0, 1, 4, 5};
  const int bh = blockIdx.x;
  const int qt = qperm[blockIdx.y];
  const int b = bh >> 4, h = bh & 15;

  bf16x8 qf[2][2];
#pragma unroll
  for (int m = 0; m < 2; m++) {
    const u16* qp =
        q + (size_t)(b * T_ + qt * 128 + wave * 32 + m * 16 + l16) * C_ + h * 64;
#pragma unroll
    for (int ks = 0; ks < 2; ks++)
      qf[m][ks] = *(const bf16x8*)(qp + ks * 32 + quad * 8);
  }

  f32x4 zero = {0.f, 0.f, 0.f, 0.f};
  f32x4 o[2][4];
  float lp[2][4];
#pragma unroll
  for (int m = 0; m < 2; m++) {
#pragma unroll
    for (int dt = 0; dt < 4; dt++) o[m][dt] = zero;
#pragma unroll
    for (int r = 0; r < 4; r++) lp[m][r] = 0.f;
  }

  const u16* kp[4];
  const u16* vp[4];
#pragma unroll
  for (int i = 0; i < 4; i++) {
    int c = i * 256 + tid;
    int r = c >> 3, lc = (c & 7) ^ (r & 7);
    kp[i] = k + (size_t)(b * T_ + r) * C_ + h * 64 + lc * 8;
  }
#pragma unroll
  for (int s = 0; s < 2; s++)
#pragma unroll
    for (int i = 0; i < 2; i++) {
      int c = i * 256 + tid;
      int r = c >> 3, lc = (c & 7) ^ (r & 7);
      vp[s * 2 + i] = vt + (size_t)(bh * 64 + r) * T_ + 64 * s + lc * 8;
    }

  int qrel[2];
#pragma unroll
  for (int m = 0; m < 2; m++)
    qrel[m] = wave * 32 + m * 16 + quad * 4 - l16;

  u16* Pw = &Psm[wave][0];

#pragma unroll 1
  for (int jt = 0; jt <= qt; ++jt) {
#pragma unroll
    for (int i = 0; i < 4; i++) {
      async16(kp[i], Ksm + (size_t)(i * 256 + wave * 64) * 8);
      kp[i] += (size_t)128 * C_;
    }
#pragma unroll
    for (int s = 0; s < 2; s++)
#pragma unroll
      for (int i = 0; i < 2; i++) {
        async16(vp[s * 2 + i], Vsm[s] + (size_t)(i * 256 + wave * 64) * 8);
        vp[s * 2 + i] += 128;
      }
    __syncthreads();

    const bool diag = (jt == qt);
#pragma unroll
    for (int hh = 0; hh < 2; ++hh) {
      if (diag && (2 * wave + 2 - 4 * hh) <= 0) continue;
#pragma unroll
      for (int n = 0; n < 4; ++n) {
        int rk = hh * 64 + n * 16 + l16;
        bf16x8 kf0 = *(const bf16x8*)(Ksm + rk * 64 + ((quad ^ (rk & 7)) * 8));
        bf16x8 kf1 = *(const bf16x8*)(Ksm + rk * 64 + (((4 + quad) ^ (rk & 7)) * 8));
#pragma unroll
        for (int m = 0; m < 2; ++m) {
          int nlim = diag ? (2 * wave + m + 1 - 4 * hh) : 4;
          if (n < nlim) {
            f32x4 s = mfma32(qf[m][0], kf0, zero);
            s = mfma32(qf[m][1], kf1, s);
            float e[4];
#pragma unroll
            for (int r = 0; r < 4; r++) e[r] = EXP2F(s[r]);
            if (diag) {
              int rmin = hh * 64 + n * 16 - qrel[m];
#pragma unroll
              for (int r = 0; r < 4; r++)
                if (r < rmin) e[r] = 0.f;
            }
#pragma unroll
            for (int r = 0; r < 4; r++) {
              lp[m][r] += e[r];
              int qr = m * 16 + quad * 4 + r;
              Pw[qr * 64 + (((n * 2 + (l16 >> 3)) ^ (qr & 7)) * 8) + (l16 & 7)] =
                  f2bf(e[r]);
            }
          } else {
#pragma unroll
            for (int r = 0; r < 4; r++) {
              int qr = m * 16 + quad * 4 + r;
              Pw[qr * 64 + (((n * 2 + (l16 >> 3)) ^ (qr & 7)) * 8) + (l16 & 7)] = 0;
            }
          }
        }
      }
      bf16x8 pf[2][2];
#pragma unroll
      for (int m = 0; m < 2; m++)
#pragma unroll
        for (int ks = 0; ks < 2; ks++)
          pf[m][ks] = *(const bf16x8*)(Pw + (m * 16 + l16) * 64 +
                                       (((ks * 4 + quad) ^ (l16 & 7)) * 8));
#pragma unroll
      for (int dt = 0; dt < 4; ++dt) {
        int rv = dt * 16 + l16;
        bf16x8 vf0 = *(const bf16x8*)(Vsm[hh] + rv * 64 + ((quad ^ (rv & 7)) * 8));
        bf16x8 vf1 = *(const bf16x8*)(Vsm[hh] + rv * 64 + (((4 + quad) ^ (rv & 7)) * 8));
#pragma unroll
        for (int m = 0; m < 2; m++) {
          o[m][dt] = mfma32(pf[m][0], vf0, o[m][dt]);
          o[m][dt] = mfma32(pf[m][1], vf1, o[m][dt]);
        }
      }
    }
    __syncthreads();
  }

#pragma unroll
  for (int m = 0; m < 2; m++)
#pragma unroll
    for (int r = 0; r < 4; r++) {
      float v = lp[m][r];
      v += __shfl_xor(v, 1);
      v += __shfl_xor(v, 2);
      v += __shfl_xor(v, 4);
      v += __shfl_xor(v, 8);
      lp[m][r] = 1.f / v;
    }

#pragma unroll
  for (int m = 0; m < 2; m++)
#pragma unroll
    for (int r = 0; r < 4; r++) {
      int grow = b * T_ + qt * 128 + wave * 32 + m * 16 + quad * 4 + r;
#pragma unroll
      for (int dt = 0; dt < 4; dt++)
        y[(size_t)grow * C_ + h * 64 + dt * 16 + l16] = f2bf(o[m][dt][r] * lp[m][r]);
    }
}

extern "C" void kernel_launch(void* const* d_in, const int* in_sizes, int n_in,
                              void* d_out, int out_size, void* d_ws, size_t ws_size,
                              hipStream_t stream) {
  const float* x  = (const float*)d_in[0];
  const float* wq = (const float*)d_in[1];
  const float* bq = (const float*)d_in[2];
  const float* wk = (const float*)d_in[3];
  const float* bk = (const float*)d_in[4];
  const float* wv = (const float*)d_in[5];
  const float* bv = (const float*)d_in[6];
  const float* wo = (const float*)d_in[7];
  const float* bo = (const float*)d_in[8];
  float* out = (float*)d_out;

  const float QSCALE = 0.125f * 1.4426950408889634f;  // hd^-0.5 * log2(e)

  u16* xb  = (u16*)d_ws;                    // [8192,1024]
  u16* wqb = xb  + (size_t)M_ * C_;         // [1024,1024] x4 (wq|wk|wv|wo contig)
  u16* wob = wqb + 3 * (size_t)C_ * C_;
  u16* qb  = wob + (size_t)C_ * C_;         // [8192,1024] (qb|kb contiguous)
  u16* kb  = qb  + (size_t)M_ * C_;
  u16* vtb = kb  + (size_t)M_ * C_;         // [(b*16+h)*64+d][2048]
  u16* yb  = xb;  // xb dead after QKV projections

  const int NCVT = (M_ * C_ + 4 * C_ * C_) / 4 / 256;  // 12288 blocks
  cvt_all<<<NCVT, 256, 0, stream>>>(x, wq, wk, wv, wo, xb, wqb, QSCALE);

  gemm_qkv<<<dim3(24, M_ / 128), 256, 0, stream>>>(xb, wqb, bq, bk, bv, QSCALE,
                                                   qb, vtb);

  attn<<<dim3(B_ * H_, 16), 256, 0, stream>>>(qb, kb, vtb, yb);

  gemm_o<<<dim3(C_ / 128, M_ / 128), 256, 0, stream>>>(yb, wob, bo, out);
}